// Round 11
// baseline (152.717 us; speedup 1.0000x reference)
//
#include <hip/hip_runtime.h>
#include <hip/hip_bf16.h>

#define ROWS   8192
#define DIM    512
#define NCODES 8192
#define NT     8                      // K-tiles of 64
#define MARGIN 3.0f

using i32x4 = __attribute__((ext_vector_type(4))) int;
typedef unsigned char u8;

__device__ __forceinline__ unsigned int pack4(int a, int b, int c, int d) {
    return (a & 255) | ((b & 255) << 8) | ((c & 255) << 16) | ((unsigned)(d & 255) << 24);
}

// ---------- Kernel 1: LN+quant(H, per-row) | quant(E, per-64-row-chunk) ----------
__global__ __launch_bounds__(256) void prep_kernel(
    const float* __restrict__ x, const float* __restrict__ lw,
    const float* __restrict__ lb, const float* __restrict__ embd,
    float2* __restrict__ stats, float* __restrict__ sh, float* __restrict__ se,
    u8* __restrict__ Hq, u8* __restrict__ Eq)
{
    __shared__ float red[4];
    const int w    = threadIdx.x >> 6;
    const int lane = threadIdx.x & 63;
    const int b    = blockIdx.x;

    if (b < 2048) {                       // ---- H rows (per-row scale) ----
        const int row = b * 4 + w;
        const float* xr = x + (size_t)row * DIM + lane * 8;
        float4 v0 = *(const float4*)(xr);
        float4 v1 = *(const float4*)(xr + 4);
        float s = (v0.x + v0.y) + (v0.z + v0.w) + (v1.x + v1.y) + (v1.z + v1.w);
        float q = v0.x*v0.x + v0.y*v0.y + v0.z*v0.z + v0.w*v0.w
                + v1.x*v1.x + v1.y*v1.y + v1.z*v1.z + v1.w*v1.w;
        #pragma unroll
        for (int off = 1; off < 64; off <<= 1) {
            s += __shfl_xor(s, off);
            q += __shfl_xor(q, off);
        }
        float mu   = s * (1.0f / DIM);
        float var  = q * (1.0f / DIM) - mu * mu;
        float rstd = rsqrtf(var + 1e-5f);
        if (lane == 0) stats[row] = make_float2(mu, rstd);

        float4 w0 = *(const float4*)(lw + lane * 8);
        float4 w1 = *(const float4*)(lw + lane * 8 + 4);
        float4 b0 = *(const float4*)(lb + lane * 8);
        float4 b1 = *(const float4*)(lb + lane * 8 + 4);
        float hv[8] = {
            (v0.x - mu) * rstd * w0.x + b0.x, (v0.y - mu) * rstd * w0.y + b0.y,
            (v0.z - mu) * rstd * w0.z + b0.z, (v0.w - mu) * rstd * w0.w + b0.w,
            (v1.x - mu) * rstd * w1.x + b1.x, (v1.y - mu) * rstd * w1.y + b1.y,
            (v1.z - mu) * rstd * w1.z + b1.z, (v1.w - mu) * rstd * w1.w + b1.w };

        float am = 0.0f;
        #pragma unroll
        for (int j = 0; j < 8; ++j) am = fmaxf(am, fabsf(hv[j]));
        #pragma unroll
        for (int off = 1; off < 64; off <<= 1) am = fmaxf(am, __shfl_xor(am, off));
        const float inv = (am > 0.0f) ? (127.0f / am) : 0.0f;
        if (lane == 0) sh[row] = am * (1.0f / 127.0f);

        int qi[8];
        #pragma unroll
        for (int j = 0; j < 8; ++j) qi[j] = __float2int_rn(hv[j] * inv);
        uint2 p = make_uint2(pack4(qi[0], qi[1], qi[2], qi[3]),
                             pack4(qi[4], qi[5], qi[6], qi[7]));
        *(uint2*)(Hq + (size_t)row * DIM + lane * 8) = p;
    } else {                              // ---- E 64-row chunks (per-chunk scale) ----
        const int chunk = b - 2048;                    // 0..127
        const int row   = chunk * 64 + (threadIdx.x >> 2);
        const int off0  = (threadIdx.x & 3) * 128;
        const float* er = embd + (size_t)row * DIM + off0;

        float4 v[32];
        float am = 0.0f;
        #pragma unroll
        for (int j = 0; j < 32; ++j) {
            v[j] = *(const float4*)(er + j * 4);
            am = fmaxf(am, fmaxf(fmaxf(fabsf(v[j].x), fabsf(v[j].y)),
                                 fmaxf(fabsf(v[j].z), fabsf(v[j].w))));
        }
        #pragma unroll
        for (int off = 1; off < 64; off <<= 1) am = fmaxf(am, __shfl_xor(am, off));
        if (lane == 0) red[w] = am;
        __syncthreads();
        am = fmaxf(fmaxf(red[0], red[1]), fmaxf(red[2], red[3]));

        const float inv = (am > 0.0f) ? (127.0f / am) : 0.0f;
        if (threadIdx.x == 0) se[chunk] = am * (1.0f / 127.0f);

        u8* out = Eq + (size_t)row * DIM + off0;
        #pragma unroll
        for (int j = 0; j < 32; j += 4) {
            uint4 o;
            o.x = pack4(__float2int_rn(v[j+0].x*inv), __float2int_rn(v[j+0].y*inv),
                        __float2int_rn(v[j+0].z*inv), __float2int_rn(v[j+0].w*inv));
            o.y = pack4(__float2int_rn(v[j+1].x*inv), __float2int_rn(v[j+1].y*inv),
                        __float2int_rn(v[j+1].z*inv), __float2int_rn(v[j+1].w*inv));
            o.z = pack4(__float2int_rn(v[j+2].x*inv), __float2int_rn(v[j+2].y*inv),
                        __float2int_rn(v[j+2].z*inv), __float2int_rn(v[j+2].w*inv));
            o.w = pack4(__float2int_rn(v[j+3].x*inv), __float2int_rn(v[j+3].y*inv),
                        __float2int_rn(v[j+3].z*inv), __float2int_rn(v[j+3].w*inv));
            *(uint4*)(out + j * 4) = o;
        }
    }
}

// ---------- Kernel 2: 1-WAVE block, direct-to-register i8 GEMM, NO LDS/barriers --
// 8192 blocks x 64 threads. Block = wave = 128x64 output tile (acc[8][4]).
// Fragments loaded straight from L2 (fragment mapping row=lane&15, kgrp=lane>>4 —
// byte-identical to R10's verified LDS reads). 1-deep ping-pong prefetch;
// compiler's per-register waitcnts give exact per-wave sync. 2 waves/SIMD,
// 8 independent blocks/CU — no barrier coupling anywhere.
__global__ __launch_bounds__(64, 2) void gemm_argmax_kernel(
    const u8* __restrict__ Hq, const u8* __restrict__ Eq,
    const float* __restrict__ sh, const float* __restrict__ se,
    float* __restrict__ pval, int* __restrict__ pidx)
{
    const int lane = threadIdx.x;      // 0..63
    const int r_   = lane & 15;
    const int g    = lane >> 4;

    // XCD map: xcd = bid&7 owns row-panels xcd*8..xcd*8+7; within an XCD the
    // 8 row-panels iterate fastest so the 32 KB B-panel stays L2-hot.
    const int bid  = blockIdx.x;
    const int rowp = ((bid & 7) << 3) | ((bid >> 3) & 7);   // 0..63
    const int colp = bid >> 6;                              // 0..127
    const int r0   = rowp * 128;
    const int n0   = colp * 64;

    const u8* Ab = Hq + (size_t)(r0 + r_) * DIM + g * 16;
    const u8* Bb = Eq + (size_t)(n0 + r_) * DIM + g * 16;

    i32x4 acc[8][4];
    #pragma unroll
    for (int m = 0; m < 8; ++m)
        #pragma unroll
        for (int n = 0; n < 4; ++n) acc[m][n] = (i32x4){0, 0, 0, 0};

    i32x4 af[2][8], bf[2][4];

#define LOADT(P, KT) do {                                              \
        _Pragma("unroll")                                              \
        for (int m = 0; m < 8; ++m)                                    \
            af[P][m] = *(const i32x4*)(Ab + (size_t)m * 16 * DIM + (KT) * 64); \
        _Pragma("unroll")                                              \
        for (int n = 0; n < 4; ++n)                                    \
            bf[P][n] = *(const i32x4*)(Bb + (size_t)n * 16 * DIM + (KT) * 64); \
    } while (0)
#define MF(M, N, AV, BV) \
        acc[M][N] = __builtin_amdgcn_mfma_i32_16x16x64_i8(AV, BV, acc[M][N], 0, 0, 0)

    LOADT(0, 0);
    #pragma unroll
    for (int t = 0; t < NT; ++t) {
        const int cur = t & 1;
        if (t + 1 < NT) LOADT(cur ^ 1, t + 1);
        __builtin_amdgcn_s_setprio(1);
        #pragma unroll
        for (int m = 0; m < 8; ++m) {
            MF(m, 0, af[cur][m], bf[cur][0]);
            MF(m, 1, af[cur][m], bf[cur][1]);
            MF(m, 2, af[cur][m], bf[cur][2]);
            MF(m, 3, af[cur][m], bf[cur][3]);
        }
        __builtin_amdgcn_s_setprio(0);
    }

#undef MF
#undef LOADT

    // ---- epilogue: pure-i32 packed-key top-2 per (row, this 64-col panel) ----
    const int   cb    = n0;
    const float se_ch = se[colp];
    #pragma unroll
    for (int m = 0; m < 8; ++m) {
        const float4 sc4 = *(const float4*)&sh[r0 + m * 16 + g * 4];
        #pragma unroll
        for (int reg = 0; reg < 4; ++reg) {
            int ka = (acc[m][0][reg] << 7) | (63 - r_);
            int kb = (acc[m][1][reg] << 7) | (47 - r_);
            int kc = (acc[m][2][reg] << 7) | (31 - r_);
            int kd = (acc[m][3][reg] << 7) | (15 - r_);
            int m1 = max(ka, kb), n1 = min(ka, kb);
            int m2 = max(kc, kd), n2 = min(kc, kd);
            int k1 = max(m1, m2);
            int k2 = max(min(m1, m2), max(n1, n2));
            #pragma unroll
            for (int off = 1; off < 16; off <<= 1) {
                int b1 = __shfl_xor(k1, off);
                int b2 = __shfl_xor(k2, off);
                k2 = max(max(k2, b2), min(k1, b1));
                k1 = max(k1, b1);
            }
            if (r_ == 0) {
                const float sc = (reg == 0) ? sc4.x : (reg == 1) ? sc4.y
                                 : (reg == 2) ? sc4.z : sc4.w;
                const int row = r0 + m * 16 + g * 4 + reg;
                const size_t base = (size_t)row * 256 + colp * 2;
                pval[base]     = (float)(k1 >> 7) * (sc * se_ch);
                pval[base + 1] = (float)(k2 >> 7) * (sc * se_ch);
                pidx[base]     = cb + 63 - (k1 & 63);
                pidx[base + 1] = cb + 63 - (k2 & 63);
            }
        }
    }
}

// ---------- Kernel 3: exact fp32 re-check of candidates + gather ----------
__global__ __launch_bounds__(256) void finalize_kernel(
    const float* __restrict__ x, const float* __restrict__ lw,
    const float* __restrict__ lb, const float* __restrict__ embd,
    const float2* __restrict__ stats,
    const float* __restrict__ pval, const int* __restrict__ pidx,
    float* __restrict__ outq, float* __restrict__ outi)
{
    const int w    = threadIdx.x >> 6;
    const int lane = threadIdx.x & 63;
    const int row  = blockIdx.x * 4 + w;

    const float4 cv = *(const float4*)&pval[(size_t)row * 256 + lane * 4];
    const int4   ci = *(const int4*)  &pidx[(size_t)row * 256 + lane * 4];
    float vv[4] = { cv.x, cv.y, cv.z, cv.w };
    int   ii[4] = { ci.x, ci.y, ci.z, ci.w };

    float M = fmaxf(fmaxf(vv[0], vv[1]), fmaxf(vv[2], vv[3]));
    #pragma unroll
    for (int off = 1; off < 64; off <<= 1) M = fmaxf(M, __shfl_xor(M, off));
    const float T = M - MARGIN;

    const float2 st = stats[row];
    const float mu = st.x, rstd = st.y;
    const float* xr = x + (size_t)row * DIM + lane * 8;
    float4 x0 = *(const float4*)(xr);
    float4 x1 = *(const float4*)(xr + 4);
    float4 w0 = *(const float4*)(lw + lane * 8);
    float4 w1 = *(const float4*)(lw + lane * 8 + 4);
    float4 b0 = *(const float4*)(lb + lane * 8);
    float4 b1 = *(const float4*)(lb + lane * 8 + 4);
    float h[8] = {
        (x0.x - mu) * rstd * w0.x + b0.x, (x0.y - mu) * rstd * w0.y + b0.y,
        (x0.z - mu) * rstd * w0.z + b0.z, (x0.w - mu) * rstd * w0.w + b0.w,
        (x1.x - mu) * rstd * w1.x + b1.x, (x1.y - mu) * rstd * w1.y + b1.y,
        (x1.z - mu) * rstd * w1.z + b1.z, (x1.w - mu) * rstd * w1.w + b1.w };

    float bestv = -3.4e38f; int besti = 0x7fffffff;
    #pragma unroll
    for (int s = 0; s < 4; ++s) {
        unsigned long long msk = __ballot(vv[s] >= T);
        while (msk) {
            const int L = __ffsll(msk) - 1;
            msk &= msk - 1;
            const int cand = __shfl(ii[s], L);
            const float* er = embd + (size_t)cand * DIM + lane * 8;
            float4 e0 = *(const float4*)er;
            float4 e1 = *(const float4*)(er + 4);
            float d = h[0]*e0.x + h[1]*e0.y + h[2]*e0.z + h[3]*e0.w
                    + h[4]*e1.x + h[5]*e1.y + h[6]*e1.z + h[7]*e1.w;
            #pragma unroll
            for (int off = 1; off < 64; off <<= 1) d += __shfl_xor(d, off);
            if (d > bestv || (d == bestv && cand < besti)) { bestv = d; besti = cand; }
        }
    }

    const float* er = embd + (size_t)besti * DIM + lane * 8;
    float4 q0 = *(const float4*)er;
    float4 q1 = *(const float4*)(er + 4);
    float* qr = outq + (size_t)row * DIM + lane * 8;
    *(float4*)(qr)     = q0;
    *(float4*)(qr + 4) = q1;
    if (lane == 0) outi[row] = (float)besti;
}

extern "C" void kernel_launch(void* const* d_in, const int* in_sizes, int n_in,
                              void* d_out, int out_size, void* d_ws, size_t ws_size,
                              hipStream_t stream) {
    const float* x    = (const float*)d_in[0];
    const float* lnw  = (const float*)d_in[1];
    const float* lnb  = (const float*)d_in[2];
    const float* embd = (const float*)d_in[3];

    float* outq = (float*)d_out;
    float* outi = outq + (size_t)ROWS * DIM;

    char* ws = (char*)d_ws;
    float2* stats = (float2*)ws;                                  // 64 KiB
    float*  sh    = (float*)(ws + (1 << 16));                     // 32 KiB
    float*  se    = (float*)(ws + (1 << 16) + (1 << 15));         // 512 B used
    u8*     Hq    = (u8*)(ws + (1 << 17));                        // 4 MiB
    u8*     Eq    = (u8*)(ws + (1 << 17) + (4 << 20));            // 4 MiB
    float*  pval  = (float*)(ws + (1 << 17) + (8 << 20));         // 8 MiB
    int*    pidx  = (int*)  (ws + (1 << 17) + (16 << 20));        // 8 MiB

    prep_kernel<<<2176, 256, 0, stream>>>(x, lnw, lnb, embd, stats, sh, se, Hq, Eq);

    gemm_argmax_kernel<<<8192, 64, 0, stream>>>(Hq, Eq, sh, se, pval, pidx);

    finalize_kernel<<<ROWS / 4, 256, 0, stream>>>(x, lnw, lnb, embd, stats,
                                                  pval, pidx, outq, outi);
}

// Round 12
// 132.493 us; speedup vs baseline: 1.1526x; 1.1526x over previous
//
#include <hip/hip_runtime.h>
#include <hip/hip_bf16.h>

#define ROWS   8192
#define DIM    512
#define NCODES 8192
#define BM     128
#define BN     64
#define BKD    128                    // double K-tile (2 x 64)
#define NT     (DIM / BKD)            // 4 double-tiles
#define MARGIN 3.0f

using i32x4 = __attribute__((ext_vector_type(4))) int;
typedef unsigned char u8;

__device__ __forceinline__ void gload_lds16(const void* g, void* l) {
    __builtin_amdgcn_global_load_lds((const __attribute__((address_space(1))) void*)g,
                                     (__attribute__((address_space(3))) void*)l,
                                     16, 0, 0);
}

__device__ __forceinline__ unsigned int pack4(int a, int b, int c, int d) {
    return (a & 255) | ((b & 255) << 8) | ((c & 255) << 16) | ((unsigned)(d & 255) << 24);
}

// ---------- Kernel 1: LN+quant(H, per-row) | quant(E, per-64-row-chunk) ----------
__global__ __launch_bounds__(256) void prep_kernel(
    const float* __restrict__ x, const float* __restrict__ lw,
    const float* __restrict__ lb, const float* __restrict__ embd,
    float2* __restrict__ stats, float* __restrict__ sh, float* __restrict__ se,
    u8* __restrict__ Hq, u8* __restrict__ Eq)
{
    __shared__ float red[4];
    const int w    = threadIdx.x >> 6;
    const int lane = threadIdx.x & 63;
    const int b    = blockIdx.x;

    if (b < 2048) {                       // ---- H rows (per-row scale) ----
        const int row = b * 4 + w;
        const float* xr = x + (size_t)row * DIM + lane * 8;
        float4 v0 = *(const float4*)(xr);
        float4 v1 = *(const float4*)(xr + 4);
        float s = (v0.x + v0.y) + (v0.z + v0.w) + (v1.x + v1.y) + (v1.z + v1.w);
        float q = v0.x*v0.x + v0.y*v0.y + v0.z*v0.z + v0.w*v0.w
                + v1.x*v1.x + v1.y*v1.y + v1.z*v1.z + v1.w*v1.w;
        #pragma unroll
        for (int off = 1; off < 64; off <<= 1) {
            s += __shfl_xor(s, off);
            q += __shfl_xor(q, off);
        }
        float mu   = s * (1.0f / DIM);
        float var  = q * (1.0f / DIM) - mu * mu;
        float rstd = rsqrtf(var + 1e-5f);
        if (lane == 0) stats[row] = make_float2(mu, rstd);

        float4 w0 = *(const float4*)(lw + lane * 8);
        float4 w1 = *(const float4*)(lw + lane * 8 + 4);
        float4 b0 = *(const float4*)(lb + lane * 8);
        float4 b1 = *(const float4*)(lb + lane * 8 + 4);
        float hv[8] = {
            (v0.x - mu) * rstd * w0.x + b0.x, (v0.y - mu) * rstd * w0.y + b0.y,
            (v0.z - mu) * rstd * w0.z + b0.z, (v0.w - mu) * rstd * w0.w + b0.w,
            (v1.x - mu) * rstd * w1.x + b1.x, (v1.y - mu) * rstd * w1.y + b1.y,
            (v1.z - mu) * rstd * w1.z + b1.z, (v1.w - mu) * rstd * w1.w + b1.w };

        float am = 0.0f;
        #pragma unroll
        for (int j = 0; j < 8; ++j) am = fmaxf(am, fabsf(hv[j]));
        #pragma unroll
        for (int off = 1; off < 64; off <<= 1) am = fmaxf(am, __shfl_xor(am, off));
        const float inv = (am > 0.0f) ? (127.0f / am) : 0.0f;
        if (lane == 0) sh[row] = am * (1.0f / 127.0f);

        int qi[8];
        #pragma unroll
        for (int j = 0; j < 8; ++j) qi[j] = __float2int_rn(hv[j] * inv);
        uint2 p = make_uint2(pack4(qi[0], qi[1], qi[2], qi[3]),
                             pack4(qi[4], qi[5], qi[6], qi[7]));
        *(uint2*)(Hq + (size_t)row * DIM + lane * 8) = p;
    } else {                              // ---- E 64-row chunks (per-chunk scale) ----
        const int chunk = b - 2048;                    // 0..127
        const int row   = chunk * 64 + (threadIdx.x >> 2);
        const int off0  = (threadIdx.x & 3) * 128;
        const float* er = embd + (size_t)row * DIM + off0;

        float4 v[32];
        float am = 0.0f;
        #pragma unroll
        for (int j = 0; j < 32; ++j) {
            v[j] = *(const float4*)(er + j * 4);
            am = fmaxf(am, fmaxf(fmaxf(fabsf(v[j].x), fabsf(v[j].y)),
                                 fmaxf(fabsf(v[j].z), fabsf(v[j].w))));
        }
        #pragma unroll
        for (int off = 1; off < 64; off <<= 1) am = fmaxf(am, __shfl_xor(am, off));
        if (lane == 0) red[w] = am;
        __syncthreads();
        am = fmaxf(fmaxf(red[0], red[1]), fmaxf(red[2], red[3]));

        const float inv = (am > 0.0f) ? (127.0f / am) : 0.0f;
        if (threadIdx.x == 0) se[chunk] = am * (1.0f / 127.0f);

        u8* out = Eq + (size_t)row * DIM + off0;
        #pragma unroll
        for (int j = 0; j < 32; j += 4) {
            uint4 o;
            o.x = pack4(__float2int_rn(v[j+0].x*inv), __float2int_rn(v[j+0].y*inv),
                        __float2int_rn(v[j+0].z*inv), __float2int_rn(v[j+0].w*inv));
            o.y = pack4(__float2int_rn(v[j+1].x*inv), __float2int_rn(v[j+1].y*inv),
                        __float2int_rn(v[j+1].z*inv), __float2int_rn(v[j+1].w*inv));
            o.z = pack4(__float2int_rn(v[j+2].x*inv), __float2int_rn(v[j+2].y*inv),
                        __float2int_rn(v[j+2].z*inv), __float2int_rn(v[j+2].w*inv));
            o.w = pack4(__float2int_rn(v[j+3].x*inv), __float2int_rn(v[j+3].y*inv),
                        __float2int_rn(v[j+3].z*inv), __float2int_rn(v[j+3].w*inv));
            *(uint4*)(out + j * 4) = o;
        }
    }
}

// ---------- Kernel 2: 128x64 i8 GEMM, acc[4][2] (32 AGPR), 3 waves/SIMD ----
// 256 threads = 4 waves (2 row x 2 col); per-wave output 64x32. K processed in
// 4 double-tiles of 128 (16 MFMA + 12 ds_read per wave between barrier pairs).
// LDS: dbuf x (A 16KB + B 8KB) + 1KB merge = 49 KB -> 3 blocks/CU; with
// ~145 regs/wave -> 3 waves/SIMD = 12 waves/CU (the TLP R3-R11 never had).
// Swizzle (128-B rows): byte ^= (r_&7)<<4 on the 8x16B slots; source
// pre-swizzled with the same involution.
__global__ __launch_bounds__(256, 3) void gemm_argmax_kernel(
    const u8* __restrict__ Hq, const u8* __restrict__ Eq,
    const float* __restrict__ sh, const float* __restrict__ se,
    float* __restrict__ pval, int* __restrict__ pidx)
{
    __shared__ __align__(16) u8 As[2][BM * BKD];  // 2 x 16 KB
    __shared__ __align__(16) u8 Bs[2][BN * BKD];  // 2 x 8 KB
    __shared__ int mrg[BM][2];                    // 1 KB cross-wave merge

    const int tid  = threadIdx.x;
    const int w    = tid >> 6;
    const int lane = tid & 63;
    const int r_   = lane & 15;
    const int g    = lane >> 4;
    const int wr   = w >> 1;          // row half (0,1) -> 64 rows
    const int wc   = w & 1;           // col half (0,1) -> 32 cols

    // XCD map: xcd = bid&7 owns 8 row-panels (512 KB A resident); within an
    // XCD the 8 row-panels iterate fastest so each 32 KB B-panel is L2-hot.
    const int bid  = blockIdx.x;
    const int rowp = ((bid & 7) << 3) | ((bid >> 3) & 7);   // 0..63
    const int colp = bid >> 6;                              // 0..127
    const int r0   = rowp * BM;
    const int n0   = colp * BN;

    // staging: A 16 segs of 1KB (4/wave), B 8 segs (2/wave). dest byte
    // d = seg*1024 + lane*16 -> drow = seg*8 + (lane>>3), dcol = (lane&7)*16;
    // inverse-swizzled SOURCE col byte = dcol ^ ((drow&7)<<4).
    const int drA0 = (w * 4 + 0) * 8 + (lane >> 3);
    const int drA1 = (w * 4 + 1) * 8 + (lane >> 3);
    const int drA2 = (w * 4 + 2) * 8 + (lane >> 3);
    const int drA3 = (w * 4 + 3) * 8 + (lane >> 3);
    const int drB0 = (w * 2 + 0) * 8 + (lane >> 3);
    const int drB1 = (w * 2 + 1) * 8 + (lane >> 3);
    const int scol = ((lane & 7) * 16) ^ (((lane >> 3) & 7) << 4);
    const u8* sA0 = Hq + (size_t)(r0 + drA0) * DIM + scol;
    const u8* sA1 = Hq + (size_t)(r0 + drA1) * DIM + scol;
    const u8* sA2 = Hq + (size_t)(r0 + drA2) * DIM + scol;
    const u8* sA3 = Hq + (size_t)(r0 + drA3) * DIM + scol;
    const u8* sB0 = Eq + (size_t)(n0 + drB0) * DIM + scol;
    const u8* sB1 = Eq + (size_t)(n0 + drB1) * DIM + scol;
    const int ua0 = (w * 4 + 0) * 1024, ua1 = (w * 4 + 1) * 1024;
    const int ua2 = (w * 4 + 2) * 1024, ua3 = (w * 4 + 3) * 1024;
    const int ub0 = (w * 2 + 0) * 1024, ub1 = (w * 2 + 1) * 1024;

    // swizzled ds_read bases: row*128 + ((th*64 + g*16) ^ fld), fld=(r_&7)<<4
    const int fld = (r_ & 7) << 4;
    const int ar  = (wr * 64 + r_) * 128;    // + m*2048
    const int br  = (wc * 32 + r_) * 128;    // + n*2048

    i32x4 acc[4][2];
    #pragma unroll
    for (int m = 0; m < 4; ++m)
        #pragma unroll
        for (int n = 0; n < 2; ++n) acc[m][n] = (i32x4){0, 0, 0, 0};

#define STAGE(D, SL) do {                                           \
        const int _ko = (D) * BKD;                                  \
        gload_lds16(sA0 + _ko, &As[SL][ua0]);                       \
        gload_lds16(sA1 + _ko, &As[SL][ua1]);                       \
        gload_lds16(sA2 + _ko, &As[SL][ua2]);                       \
        gload_lds16(sA3 + _ko, &As[SL][ua3]);                       \
        gload_lds16(sB0 + _ko, &Bs[SL][ub0]);                       \
        gload_lds16(sB1 + _ko, &Bs[SL][ub1]);                       \
    } while (0)
#define MF(M, N, AV, BV) \
        acc[M][N] = __builtin_amdgcn_mfma_i32_16x16x64_i8(AV, BV, acc[M][N], 0, 0, 0)

#define K_TILE(SL, STG, VMSTR) do {                                 \
        STG;                                                        \
        asm volatile("s_waitcnt vmcnt(" VMSTR ")" ::: "memory");    \
        __builtin_amdgcn_s_barrier();                               \
        const u8* Ab = &As[SL][0];                                  \
        const u8* Bb = &Bs[SL][0];                                  \
        const int ao0 = (g * 16) ^ fld;                             \
        i32x4 a0 = *(const i32x4*)(Ab + ar + ao0 + 0 * 2048);       \
        i32x4 a1 = *(const i32x4*)(Ab + ar + ao0 + 1 * 2048);       \
        i32x4 a2 = *(const i32x4*)(Ab + ar + ao0 + 2 * 2048);       \
        i32x4 a3 = *(const i32x4*)(Ab + ar + ao0 + 3 * 2048);       \
        i32x4 b0 = *(const i32x4*)(Bb + br + ao0 + 0 * 2048);       \
        i32x4 b1 = *(const i32x4*)(Bb + br + ao0 + 1 * 2048);       \
        __builtin_amdgcn_s_setprio(1);                              \
        MF(0, 0, a0, b0); MF(0, 1, a0, b1);                         \
        MF(1, 0, a1, b0); MF(1, 1, a1, b1);                         \
        MF(2, 0, a2, b0); MF(2, 1, a2, b1);                         \
        MF(3, 0, a3, b0); MF(3, 1, a3, b1);                         \
        __builtin_amdgcn_s_setprio(0);                              \
        const int ao1 = (64 + g * 16) ^ fld;                        \
        a0 = *(const i32x4*)(Ab + ar + ao1 + 0 * 2048);             \
        a1 = *(const i32x4*)(Ab + ar + ao1 + 1 * 2048);             \
        a2 = *(const i32x4*)(Ab + ar + ao1 + 2 * 2048);             \
        a3 = *(const i32x4*)(Ab + ar + ao1 + 3 * 2048);             \
        b0 = *(const i32x4*)(Bb + br + ao1 + 0 * 2048);             \
        b1 = *(const i32x4*)(Bb + br + ao1 + 1 * 2048);             \
        __builtin_amdgcn_s_setprio(1);                              \
        MF(0, 0, a0, b0); MF(0, 1, a0, b1);                         \
        MF(1, 0, a1, b0); MF(1, 1, a1, b1);                         \
        MF(2, 0, a2, b0); MF(2, 1, a2, b1);                         \
        MF(3, 0, a3, b0); MF(3, 1, a3, b1);                         \
        __builtin_amdgcn_s_setprio(0);                              \
        __builtin_amdgcn_s_barrier();                               \
    } while (0)

    // prologue: double-tile 0 staged; loop keeps 1 double (2 K-64) in flight
    STAGE(0, 0);
    K_TILE(0, STAGE(1, 1), "6");   // dtile 0
    K_TILE(1, STAGE(2, 0), "6");   // dtile 1
    K_TILE(0, STAGE(3, 1), "6");   // dtile 2
    K_TILE(1, , "0");              // dtile 3

#undef K_TILE
#undef MF
#undef STAGE

    // ---- epilogue: packed-key top-2 per wave, then cross-wave LDS merge ----
    // key field = 63 - (wc*32 + n*16 + r_) spans the full 64-col panel, so
    // keys from the two col-waves compare directly.
    const float se_ch = se[colp];
    int k1s[4][4], k2s[4][4];
    #pragma unroll
    for (int m = 0; m < 4; ++m) {
        #pragma unroll
        for (int reg = 0; reg < 4; ++reg) {
            int ka = (acc[m][0][reg] << 7) | (63 - (wc * 32 + r_));
            int kb = (acc[m][1][reg] << 7) | (63 - (wc * 32 + 16 + r_));
            int k1 = max(ka, kb);
            int k2 = min(ka, kb);
            #pragma unroll
            for (int off = 1; off < 16; off <<= 1) {
                int b1 = __shfl_xor(k1, off);
                int b2 = __shfl_xor(k2, off);
                k2 = max(max(k2, b2), min(k1, b1));
                k1 = max(k1, b1);
            }
            k1s[m][reg] = k1; k2s[m][reg] = k2;
            if (wc == 1 && r_ == 0) {
                const int lrow = wr * 64 + m * 16 + g * 4 + reg;
                mrg[lrow][0] = k1; mrg[lrow][1] = k2;
            }
        }
    }
    __syncthreads();
    if (wc == 0 && r_ == 0) {
        #pragma unroll
        for (int m = 0; m < 4; ++m) {
            #pragma unroll
            for (int reg = 0; reg < 4; ++reg) {
                const int lrow = wr * 64 + m * 16 + g * 4 + reg;
                const int k1a = k1s[m][reg], k2a = k2s[m][reg];
                const int k1b = mrg[lrow][0], k2b = mrg[lrow][1];
                const int K1 = max(k1a, k1b);
                const int K2 = max(min(k1a, k1b), max(k2a, k2b));
                const int row = r0 + lrow;
                const float sc = sh[row];
                const size_t base = (size_t)row * 256 + colp * 2;
                pval[base]     = (float)(K1 >> 7) * (sc * se_ch);
                pval[base + 1] = (float)(K2 >> 7) * (sc * se_ch);
                pidx[base]     = n0 + 63 - (K1 & 63);
                pidx[base + 1] = n0 + 63 - (K2 & 63);
            }
        }
    }
}

// ---------- Kernel 3: exact fp32 re-check of candidates + gather ----------
__global__ __launch_bounds__(256) void finalize_kernel(
    const float* __restrict__ x, const float* __restrict__ lw,
    const float* __restrict__ lb, const float* __restrict__ embd,
    const float2* __restrict__ stats,
    const float* __restrict__ pval, const int* __restrict__ pidx,
    float* __restrict__ outq, float* __restrict__ outi)
{
    const int w    = threadIdx.x >> 6;
    const int lane = threadIdx.x & 63;
    const int row  = blockIdx.x * 4 + w;

    const float4 cv = *(const float4*)&pval[(size_t)row * 256 + lane * 4];
    const int4   ci = *(const int4*)  &pidx[(size_t)row * 256 + lane * 4];
    float vv[4] = { cv.x, cv.y, cv.z, cv.w };
    int   ii[4] = { ci.x, ci.y, ci.z, ci.w };

    float M = fmaxf(fmaxf(vv[0], vv[1]), fmaxf(vv[2], vv[3]));
    #pragma unroll
    for (int off = 1; off < 64; off <<= 1) M = fmaxf(M, __shfl_xor(M, off));
    const float T = M - MARGIN;

    const float2 st = stats[row];
    const float mu = st.x, rstd = st.y;
    const float* xr = x + (size_t)row * DIM + lane * 8;
    float4 x0 = *(const float4*)(xr);
    float4 x1 = *(const float4*)(xr + 4);
    float4 w0 = *(const float4*)(lw + lane * 8);
    float4 w1 = *(const float4*)(lw + lane * 8 + 4);
    float4 b0 = *(const float4*)(lb + lane * 8);
    float4 b1 = *(const float4*)(lb + lane * 8 + 4);
    float h[8] = {
        (x0.x - mu) * rstd * w0.x + b0.x, (x0.y - mu) * rstd * w0.y + b0.y,
        (x0.z - mu) * rstd * w0.z + b0.z, (x0.w - mu) * rstd * w0.w + b0.w,
        (x1.x - mu) * rstd * w1.x + b1.x, (x1.y - mu) * rstd * w1.y + b1.y,
        (x1.z - mu) * rstd * w1.z + b1.z, (x1.w - mu) * rstd * w1.w + b1.w };

    float bestv = -3.4e38f; int besti = 0x7fffffff;
    #pragma unroll
    for (int s = 0; s < 4; ++s) {
        unsigned long long msk = __ballot(vv[s] >= T);
        while (msk) {
            const int L = __ffsll(msk) - 1;
            msk &= msk - 1;
            const int cand = __shfl(ii[s], L);
            const float* er = embd + (size_t)cand * DIM + lane * 8;
            float4 e0 = *(const float4*)er;
            float4 e1 = *(const float4*)(er + 4);
            float d = h[0]*e0.x + h[1]*e0.y + h[2]*e0.z + h[3]*e0.w
                    + h[4]*e1.x + h[5]*e1.y + h[6]*e1.z + h[7]*e1.w;
            #pragma unroll
            for (int off = 1; off < 64; off <<= 1) d += __shfl_xor(d, off);
            if (d > bestv || (d == bestv && cand < besti)) { bestv = d; besti = cand; }
        }
    }

    const float* er = embd + (size_t)besti * DIM + lane * 8;
    float4 q0 = *(const float4*)er;
    float4 q1 = *(const float4*)(er + 4);
    float* qr = outq + (size_t)row * DIM + lane * 8;
    *(float4*)(qr)     = q0;
    *(float4*)(qr + 4) = q1;
    if (lane == 0) outi[row] = (float)besti;
}

extern "C" void kernel_launch(void* const* d_in, const int* in_sizes, int n_in,
                              void* d_out, int out_size, void* d_ws, size_t ws_size,
                              hipStream_t stream) {
    const float* x    = (const float*)d_in[0];
    const float* lnw  = (const float*)d_in[1];
    const float* lnb  = (const float*)d_in[2];
    const float* embd = (const float*)d_in[3];

    float* outq = (float*)d_out;
    float* outi = outq + (size_t)ROWS * DIM;

    char* ws = (char*)d_ws;
    float2* stats = (float2*)ws;                                  // 64 KiB
    float*  sh    = (float*)(ws + (1 << 16));                     // 32 KiB
    float*  se    = (float*)(ws + (1 << 16) + (1 << 15));         // 512 B used
    u8*     Hq    = (u8*)(ws + (1 << 17));                        // 4 MiB
    u8*     Eq    = (u8*)(ws + (1 << 17) + (4 << 20));            // 4 MiB
    float*  pval  = (float*)(ws + (1 << 17) + (8 << 20));         // 8 MiB
    int*    pidx  = (int*)  (ws + (1 << 17) + (16 << 20));        // 8 MiB

    prep_kernel<<<2176, 256, 0, stream>>>(x, lnw, lnb, embd, stats, sh, se, Hq, Eq);

    gemm_argmax_kernel<<<8192, 256, 0, stream>>>(Hq, Eq, sh, se, pval, pidx);

    finalize_kernel<<<ROWS / 4, 256, 0, stream>>>(x, lnw, lnb, embd, stats,
                                                  pval, pidx, outq, outi);
}

// Round 13
// 114.278 us; speedup vs baseline: 1.3364x; 1.1594x over previous
//
#include <hip/hip_runtime.h>
#include <hip/hip_bf16.h>

#define ROWS   8192
#define DIM    512
#define NCODES 8192
#define BM     128
#define CGW    1024                   // col-group per block
#define NNT    8                      // col-tiles of 128
#define NKT    8                      // K-tiles of 64
#define MARGIN 3.0f

using i32x4 = __attribute__((ext_vector_type(4))) int;
typedef unsigned char u8;

__device__ __forceinline__ void gload_lds16(const void* g, void* l) {
    __builtin_amdgcn_global_load_lds((const __attribute__((address_space(1))) void*)g,
                                     (__attribute__((address_space(3))) void*)l,
                                     16, 0, 0);
}

__device__ __forceinline__ unsigned int pack4(int a, int b, int c, int d) {
    return (a & 255) | ((b & 255) << 8) | ((c & 255) << 16) | ((unsigned)(d & 255) << 24);
}

// ---------- Kernel 1: LN+quant(H, per-row) | quant(E, per-64-row-chunk) ----------
__global__ __launch_bounds__(256) void prep_kernel(
    const float* __restrict__ x, const float* __restrict__ lw,
    const float* __restrict__ lb, const float* __restrict__ embd,
    float2* __restrict__ stats, float* __restrict__ sh, float* __restrict__ se,
    u8* __restrict__ Hq, u8* __restrict__ Eq)
{
    __shared__ float red[4];
    const int w    = threadIdx.x >> 6;
    const int lane = threadIdx.x & 63;
    const int b    = blockIdx.x;

    if (b < 2048) {                       // ---- H rows (per-row scale) ----
        const int row = b * 4 + w;
        const float* xr = x + (size_t)row * DIM + lane * 8;
        float4 v0 = *(const float4*)(xr);
        float4 v1 = *(const float4*)(xr + 4);
        float s = (v0.x + v0.y) + (v0.z + v0.w) + (v1.x + v1.y) + (v1.z + v1.w);
        float q = v0.x*v0.x + v0.y*v0.y + v0.z*v0.z + v0.w*v0.w
                + v1.x*v1.x + v1.y*v1.y + v1.z*v1.z + v1.w*v1.w;
        #pragma unroll
        for (int off = 1; off < 64; off <<= 1) {
            s += __shfl_xor(s, off);
            q += __shfl_xor(q, off);
        }
        float mu   = s * (1.0f / DIM);
        float var  = q * (1.0f / DIM) - mu * mu;
        float rstd = rsqrtf(var + 1e-5f);
        if (lane == 0) stats[row] = make_float2(mu, rstd);

        float4 w0 = *(const float4*)(lw + lane * 8);
        float4 w1 = *(const float4*)(lw + lane * 8 + 4);
        float4 b0 = *(const float4*)(lb + lane * 8);
        float4 b1 = *(const float4*)(lb + lane * 8 + 4);
        float hv[8] = {
            (v0.x - mu) * rstd * w0.x + b0.x, (v0.y - mu) * rstd * w0.y + b0.y,
            (v0.z - mu) * rstd * w0.z + b0.z, (v0.w - mu) * rstd * w0.w + b0.w,
            (v1.x - mu) * rstd * w1.x + b1.x, (v1.y - mu) * rstd * w1.y + b1.y,
            (v1.z - mu) * rstd * w1.z + b1.z, (v1.w - mu) * rstd * w1.w + b1.w };

        float am = 0.0f;
        #pragma unroll
        for (int j = 0; j < 8; ++j) am = fmaxf(am, fabsf(hv[j]));
        #pragma unroll
        for (int off = 1; off < 64; off <<= 1) am = fmaxf(am, __shfl_xor(am, off));
        const float inv = (am > 0.0f) ? (127.0f / am) : 0.0f;
        if (lane == 0) sh[row] = am * (1.0f / 127.0f);

        int qi[8];
        #pragma unroll
        for (int j = 0; j < 8; ++j) qi[j] = __float2int_rn(hv[j] * inv);
        uint2 p = make_uint2(pack4(qi[0], qi[1], qi[2], qi[3]),
                             pack4(qi[4], qi[5], qi[6], qi[7]));
        *(uint2*)(Hq + (size_t)row * DIM + lane * 8) = p;
    } else {                              // ---- E 64-row chunks (per-chunk scale) ----
        const int chunk = b - 2048;                    // 0..127
        const int row   = chunk * 64 + (threadIdx.x >> 2);
        const int off0  = (threadIdx.x & 3) * 128;
        const float* er = embd + (size_t)row * DIM + off0;

        float4 v[32];
        float am = 0.0f;
        #pragma unroll
        for (int j = 0; j < 32; ++j) {
            v[j] = *(const float4*)(er + j * 4);
            am = fmaxf(am, fmaxf(fmaxf(fabsf(v[j].x), fabsf(v[j].y)),
                                 fmaxf(fabsf(v[j].z), fabsf(v[j].w))));
        }
        #pragma unroll
        for (int off = 1; off < 64; off <<= 1) am = fmaxf(am, __shfl_xor(am, off));
        if (lane == 0) red[w] = am;
        __syncthreads();
        am = fmaxf(fmaxf(red[0], red[1]), fmaxf(red[2], red[3]));

        const float inv = (am > 0.0f) ? (127.0f / am) : 0.0f;
        if (threadIdx.x == 0) se[chunk] = am * (1.0f / 127.0f);

        u8* out = Eq + (size_t)row * DIM + off0;
        #pragma unroll
        for (int j = 0; j < 32; j += 4) {
            uint4 o;
            o.x = pack4(__float2int_rn(v[j+0].x*inv), __float2int_rn(v[j+0].y*inv),
                        __float2int_rn(v[j+0].z*inv), __float2int_rn(v[j+0].w*inv));
            o.y = pack4(__float2int_rn(v[j+1].x*inv), __float2int_rn(v[j+1].y*inv),
                        __float2int_rn(v[j+1].z*inv), __float2int_rn(v[j+1].w*inv));
            o.z = pack4(__float2int_rn(v[j+2].x*inv), __float2int_rn(v[j+2].y*inv),
                        __float2int_rn(v[j+2].z*inv), __float2int_rn(v[j+2].w*inv));
            o.w = pack4(__float2int_rn(v[j+3].x*inv), __float2int_rn(v[j+3].y*inv),
                        __float2int_rn(v[j+3].z*inv), __float2int_rn(v[j+3].w*inv));
            *(uint4*)(out + j * 4) = o;
        }
    }
}

// ---------- Kernel 2: A-panel-resident i8 GEMM, 64 iters/block, dbuf B ----
// 512 blocks (2/CU, one generation), 256 threads = 4 waves (2 row x 2 col).
// Block = 128 rows x 1024 cols. A-panel 64 KB LDS, staged ONCE, XOR-swizzled
// (byte ^= (row&7)<<4, pre-swizzled source). B streamed as [128 col][64 k]
// 8 KB tiles (R10-verified geometry+swizzle), 2-slot dbuf, vmcnt(2).
// Per iter/wave: 8 ds_read + 16 MFMA (acc[4][4]); 64 iters amortize all
// fixed costs 8x vs R10. XCD: colg=bid&7 -> per-XCD 512 KB B stream L2-hot.
__global__ __launch_bounds__(256, 2) void gemm_argmax_kernel(
    const u8* __restrict__ Hq, const u8* __restrict__ Eq,
    const float* __restrict__ sh, const float* __restrict__ se,
    float* __restrict__ pval, int* __restrict__ pidx)
{
    __shared__ __align__(16) u8 Apan[BM * DIM];     // 64 KB
    __shared__ __align__(16) u8 Bs[2][128 * 64];    // 16 KB

    const int tid  = threadIdx.x;
    const int w    = tid >> 6;
    const int lane = tid & 63;
    const int r_   = lane & 15;
    const int g    = lane >> 4;
    const int wr   = w >> 1;          // row half: 64 rows
    const int wc   = w & 1;           // col half: 64 of the 128-col tile

    const int bid  = blockIdx.x;
    const int colg = bid & 7;         // XCD id -> col-group (L2-resident B)
    const int rowp = bid >> 3;        // 0..63
    const int r0   = rowp * BM;
    const int c0   = colg * CGW;

    // ---- one-time A-panel stage: LDS[row][c] = Hq[r0+row][c ^ ((row&7)<<4)]
    // dest d = j*1024 + lane*16 (j = w*16+jj): drow = j*2+(lane>>5),
    // dcol = (lane&31)*16; per-lane swizzled source, wave-uniform LDS base.
    #pragma unroll
    for (int jj = 0; jj < 16; ++jj) {
        const int j    = w * 16 + jj;
        const int drow = j * 2 + (lane >> 5);
        const int dcol = (lane & 31) * 16;
        gload_lds16(Hq + (size_t)(r0 + drow) * DIM + (dcol ^ ((drow & 7) << 4)),
                    &Apan[j * 1024]);
    }

    // ---- B staging geometry (R10-verified): dest d = seg*1024 + lane*16,
    // drow = seg*16+(lane>>2), dcol = (lane&3)*16, src col = dcol^((drow>>1)&3)<<4
    const int db0 = (w * 2 + 0) * 16 + (lane >> 2);
    const int db1 = (w * 2 + 1) * 16 + (lane >> 2);
    const int lc  = (lane & 3) * 16;
    const u8* sB0 = Eq + (size_t)(c0 + db0) * DIM + (lc ^ (((db0 >> 1) & 3) << 4));
    const u8* sB1 = Eq + (size_t)(c0 + db1) * DIM + (lc ^ (((db1 >> 1) & 3) << 4));
    const int ub0 = (w * 2 + 0) * 1024, ub1 = (w * 2 + 1) * 1024;

    // ds_read bases
    const int fldA = (r_ & 7) << 4;
    const int ab   = (wr * 64 + r_) * 512;   // + m*8192 + ((kt*64+g*16)^fldA)
    const int bb   = (wc * 64 + r_) * 64 + ((g * 16) ^ (((r_ >> 1) & 3) << 4)); // + n*1024

#define STAGE_B(NT2, KT2, SL) do {                                      \
        const size_t off_ = (size_t)(NT2) * (128 * DIM) + (KT2) * 64;   \
        gload_lds16(sB0 + off_, &Bs[SL][ub0]);                          \
        gload_lds16(sB1 + off_, &Bs[SL][ub1]);                          \
    } while (0)
#define MF(M, N, AV, BV) \
        acc[M][N] = __builtin_amdgcn_mfma_i32_16x16x64_i8(AV, BV, acc[M][N], 0, 0, 0)

    STAGE_B(0, 0, 0);

    for (int nt = 0; nt < NNT; ++nt) {
        i32x4 acc[4][4];
        #pragma unroll
        for (int m = 0; m < 4; ++m)
            #pragma unroll
            for (int n = 0; n < 4; ++n) acc[m][n] = (i32x4){0, 0, 0, 0};

        #pragma unroll
        for (int kt = 0; kt < NKT; ++kt) {
            // stage next B-tile into the other slot; counted vmcnt(2)
            if (kt < 7) {
                STAGE_B(nt, kt + 1, (kt + 1) & 1);
                asm volatile("s_waitcnt vmcnt(2)" ::: "memory");
            } else if (nt < 7) {
                STAGE_B(nt + 1, 0, 0);
                asm volatile("s_waitcnt vmcnt(2)" ::: "memory");
            } else {
                asm volatile("s_waitcnt vmcnt(0)" ::: "memory");
            }
            __builtin_amdgcn_s_barrier();

            const int ak = (kt * 64 + g * 16) ^ fldA;
            i32x4 a0 = *(const i32x4*)&Apan[ab + 0 * 8192 + ak];
            i32x4 a1 = *(const i32x4*)&Apan[ab + 1 * 8192 + ak];
            i32x4 a2 = *(const i32x4*)&Apan[ab + 2 * 8192 + ak];
            i32x4 a3 = *(const i32x4*)&Apan[ab + 3 * 8192 + ak];
            const u8* Bp = &Bs[kt & 1][0];
            i32x4 b0 = *(const i32x4*)(Bp + bb + 0 * 1024);
            i32x4 b1 = *(const i32x4*)(Bp + bb + 1 * 1024);
            i32x4 b2 = *(const i32x4*)(Bp + bb + 2 * 1024);
            i32x4 b3 = *(const i32x4*)(Bp + bb + 3 * 1024);

            __builtin_amdgcn_s_setprio(1);
            MF(0, 0, a0, b0); MF(0, 1, a0, b1); MF(0, 2, a0, b2); MF(0, 3, a0, b3);
            MF(1, 0, a1, b0); MF(1, 1, a1, b1); MF(1, 2, a1, b2); MF(1, 3, a1, b3);
            MF(2, 0, a2, b0); MF(2, 1, a2, b1); MF(2, 2, a2, b2); MF(2, 3, a2, b3);
            MF(3, 0, a3, b0); MF(3, 1, a3, b1); MF(3, 2, a3, b2); MF(3, 3, a3, b3);
            __builtin_amdgcn_s_setprio(0);

            __builtin_amdgcn_s_barrier();
        }

        // ---- per-nt epilogue: packed-key top-2 over this wave's 64-col chunk
        const int chunk = colg * 16 + nt * 2 + wc;   // global col/64
        const int cb    = chunk * 64;
        const float se_ch = se[chunk];
        #pragma unroll
        for (int m = 0; m < 4; ++m) {
            #pragma unroll
            for (int reg = 0; reg < 4; ++reg) {
                int ka = (acc[m][0][reg] << 7) | (63 - r_);
                int kb = (acc[m][1][reg] << 7) | (47 - r_);
                int kc = (acc[m][2][reg] << 7) | (31 - r_);
                int kd = (acc[m][3][reg] << 7) | (15 - r_);
                int m1 = max(ka, kb), n1 = min(ka, kb);
                int m2 = max(kc, kd), n2 = min(kc, kd);
                int k1 = max(m1, m2);
                int k2 = max(min(m1, m2), max(n1, n2));
                #pragma unroll
                for (int off = 1; off < 16; off <<= 1) {
                    int o1 = __shfl_xor(k1, off);
                    int o2 = __shfl_xor(k2, off);
                    k2 = max(max(k2, o2), min(k1, o1));
                    k1 = max(k1, o1);
                }
                if (r_ == 0) {
                    const int row = r0 + wr * 64 + m * 16 + g * 4 + reg;
                    const float sc = sh[row];
                    const size_t base = (size_t)row * 256 + chunk * 2;
                    pval[base]     = (float)(k1 >> 7) * (sc * se_ch);
                    pval[base + 1] = (float)(k2 >> 7) * (sc * se_ch);
                    pidx[base]     = cb + 63 - (k1 & 63);
                    pidx[base + 1] = cb + 63 - (k2 & 63);
                }
            }
        }
    }

#undef MF
#undef STAGE_B
}

// ---------- Kernel 3: exact fp32 re-check of candidates + gather ----------
__global__ __launch_bounds__(256) void finalize_kernel(
    const float* __restrict__ x, const float* __restrict__ lw,
    const float* __restrict__ lb, const float* __restrict__ embd,
    const float2* __restrict__ stats,
    const float* __restrict__ pval, const int* __restrict__ pidx,
    float* __restrict__ outq, float* __restrict__ outi)
{
    const int w    = threadIdx.x >> 6;
    const int lane = threadIdx.x & 63;
    const int row  = blockIdx.x * 4 + w;

    const float4 cv = *(const float4*)&pval[(size_t)row * 256 + lane * 4];
    const int4   ci = *(const int4*)  &pidx[(size_t)row * 256 + lane * 4];
    float vv[4] = { cv.x, cv.y, cv.z, cv.w };
    int   ii[4] = { ci.x, ci.y, ci.z, ci.w };

    float M = fmaxf(fmaxf(vv[0], vv[1]), fmaxf(vv[2], vv[3]));
    #pragma unroll
    for (int off = 1; off < 64; off <<= 1) M = fmaxf(M, __shfl_xor(M, off));
    const float T = M - MARGIN;

    const float2 st = stats[row];
    const float mu = st.x, rstd = st.y;
    const float* xr = x + (size_t)row * DIM + lane * 8;
    float4 x0 = *(const float4*)(xr);
    float4 x1 = *(const float4*)(xr + 4);
    float4 w0 = *(const float4*)(lw + lane * 8);
    float4 w1 = *(const float4*)(lw + lane * 8 + 4);
    float4 b0 = *(const float4*)(lb + lane * 8);
    float4 b1 = *(const float4*)(lb + lane * 8 + 4);
    float h[8] = {
        (x0.x - mu) * rstd * w0.x + b0.x, (x0.y - mu) * rstd * w0.y + b0.y,
        (x0.z - mu) * rstd * w0.z + b0.z, (x0.w - mu) * rstd * w0.w + b0.w,
        (x1.x - mu) * rstd * w1.x + b1.x, (x1.y - mu) * rstd * w1.y + b1.y,
        (x1.z - mu) * rstd * w1.z + b1.z, (x1.w - mu) * rstd * w1.w + b1.w };

    float bestv = -3.4e38f; int besti = 0x7fffffff;
    #pragma unroll
    for (int s = 0; s < 4; ++s) {
        unsigned long long msk = __ballot(vv[s] >= T);
        while (msk) {
            const int L = __ffsll(msk) - 1;
            msk &= msk - 1;
            const int cand = __shfl(ii[s], L);
            const float* er = embd + (size_t)cand * DIM + lane * 8;
            float4 e0 = *(const float4*)er;
            float4 e1 = *(const float4*)(er + 4);
            float d = h[0]*e0.x + h[1]*e0.y + h[2]*e0.z + h[3]*e0.w
                    + h[4]*e1.x + h[5]*e1.y + h[6]*e1.z + h[7]*e1.w;
            #pragma unroll
            for (int off = 1; off < 64; off <<= 1) d += __shfl_xor(d, off);
            if (d > bestv || (d == bestv && cand < besti)) { bestv = d; besti = cand; }
        }
    }

    const float* er = embd + (size_t)besti * DIM + lane * 8;
    float4 q0 = *(const float4*)er;
    float4 q1 = *(const float4*)(er + 4);
    float* qr = outq + (size_t)row * DIM + lane * 8;
    *(float4*)(qr)     = q0;
    *(float4*)(qr + 4) = q1;
    if (lane == 0) outi[row] = (float)besti;
}

extern "C" void kernel_launch(void* const* d_in, const int* in_sizes, int n_in,
                              void* d_out, int out_size, void* d_ws, size_t ws_size,
                              hipStream_t stream) {
    const float* x    = (const float*)d_in[0];
    const float* lnw  = (const float*)d_in[1];
    const float* lnb  = (const float*)d_in[2];
    const float* embd = (const float*)d_in[3];

    float* outq = (float*)d_out;
    float* outi = outq + (size_t)ROWS * DIM;

    char* ws = (char*)d_ws;
    float2* stats = (float2*)ws;                                  // 64 KiB
    float*  sh    = (float*)(ws + (1 << 16));                     // 32 KiB
    float*  se    = (float*)(ws + (1 << 16) + (1 << 15));         // 512 B used
    u8*     Hq    = (u8*)(ws + (1 << 17));                        // 4 MiB
    u8*     Eq    = (u8*)(ws + (1 << 17) + (4 << 20));            // 4 MiB
    float*  pval  = (float*)(ws + (1 << 17) + (8 << 20));         // 8 MiB
    int*    pidx  = (int*)  (ws + (1 << 17) + (16 << 20));        // 8 MiB

    prep_kernel<<<2176, 256, 0, stream>>>(x, lnw, lnb, embd, stats, sh, se, Hq, Eq);

    gemm_argmax_kernel<<<512, 256, 0, stream>>>(Hq, Eq, sh, se, pval, pidx);

    finalize_kernel<<<ROWS / 4, 256, 0, stream>>>(x, lnw, lnb, embd, stats,
                                                  pval, pidx, outq, outi);
}